// Round 1
// baseline (1155.145 us; speedup 1.0000x reference)
//
#include <hip/hip_runtime.h>
#include <math.h>

// Problem constants (B=8, S=2048, T=128)
#define S_LEN 2048
#define T_DIM 128
#define BM 32          // tokens per block in main kernel
#define M_TOTAL 16384  // B*S

// ---------------------------------------------------------------------------
// Kernel 1: initialize out[b,i,t] = sum(w_red)*tanh(b_comp[t]) + b_red.
// Each block independently reduces w_red (2048 floats, L2-hot) and writes
// 1024 contiguous floats of out. Grid = 2M/1024 = 2048 blocks.
// ---------------------------------------------------------------------------
__global__ __launch_bounds__(256) void init_out_kernel(
    const float* __restrict__ w_red, const float* __restrict__ b_comp,
    const float* __restrict__ b_red, float* __restrict__ out) {
  __shared__ float red[4];
  const int tid = threadIdx.x;

  float part = 0.f;
#pragma unroll
  for (int i = 0; i < 8; ++i) part += w_red[tid * 8 + i];
  // wave (64-lane) reduction
#pragma unroll
  for (int off = 32; off > 0; off >>= 1) part += __shfl_down(part, off, 64);
  if ((tid & 63) == 0) red[tid >> 6] = part;
  __syncthreads();
  const float Sw = red[0] + red[1] + red[2] + red[3];
  const float br = b_red[0];

  const size_t base = (size_t)blockIdx.x * 1024 + (size_t)tid * 4;
  const int t0 = (int)(base & 127);
  float4 v;
  v.x = Sw * tanhf(b_comp[t0 + 0]) + br;
  v.y = Sw * tanhf(b_comp[t0 + 1]) + br;
  v.z = Sw * tanhf(b_comp[t0 + 2]) + br;
  v.w = Sw * tanhf(b_comp[t0 + 3]) + br;
  *(float4*)(out + base) = v;
}

// ---------------------------------------------------------------------------
// Kernel 2: main bilinear + tanh + scatter-add.
// val[m,t] = sum_p token[m,p] * (sum_q W[t,p,q] * h[m,q])
// Block: 32 tokens, 256 threads; thread tile 4m x 4t (t strided by 32 so the
// Wp[t][q] scalar LDS reads land on distinct banks: bank=(t+q)%32).
// W staged per (p, q-half): Wp[128][65] = 33.3 KB; hT[128][36] = 18.4 KB.
// Total LDS 51.7 KB -> 3 blocks/CU.
// ---------------------------------------------------------------------------
__global__ __launch_bounds__(256) void main_kernel(
    const float* __restrict__ tok, const int* __restrict__ heads,
    const float* __restrict__ W, const float* __restrict__ b_comp,
    const float* __restrict__ w_red, float* __restrict__ out) {
  __shared__ float hT[128][36];   // hT[q][m], padded stride 36 (144B, 16B-aligned rows)
  __shared__ float Wp[128][65];   // Wp[t][q'], q' in a 64-wide half; stride 65 -> conflict-free reads

  const int tid = threadIdx.x;
  const int tt = tid & 31;   // t-group: thread's t values are tt + 32*i
  const int tm = tid >> 5;   // m-group: thread's m values are tm*4 + j
  const int m0 = tm * 4;
  const int blk = blockIdx.x;
  const size_t tokbase = (size_t)blk * BM * T_DIM;

  // Stage h = tanh(token) transposed into LDS: hT[p][m]
#pragma unroll
  for (int r = 0; r < 4; ++r) {
    const int flat = (r * 256 + tid) * 4;  // 0..4095 over [m][p]
    const int m = flat >> 7;
    const int p0 = flat & 127;
    const float4 v = *(const float4*)(tok + tokbase + (size_t)m * T_DIM + p0);
    hT[p0 + 0][m] = tanhf(v.x);
    hT[p0 + 1][m] = tanhf(v.y);
    hT[p0 + 2][m] = tanhf(v.z);
    hT[p0 + 3][m] = tanhf(v.w);
  }

  float acc[4][4];
#pragma unroll
  for (int i = 0; i < 4; ++i)
#pragma unroll
    for (int j = 0; j < 4; ++j) acc[i][j] = 0.f;

  for (int p = 0; p < 128; ++p) {
    // token[m,p] for this thread's 4 m's: global scalar loads, wave-broadcast,
    // L1-resident (32 rows * 512B re-read per p). Loaded early, used after q-loops.
    float tokv[4];
#pragma unroll
    for (int j = 0; j < 4; ++j)
      tokv[j] = tok[tokbase + (size_t)(m0 + j) * T_DIM + p];

    float inner[4][4];
#pragma unroll
    for (int i = 0; i < 4; ++i)
#pragma unroll
      for (int j = 0; j < 4; ++j) inner[i][j] = 0.f;

    for (int qh = 0; qh < 2; ++qh) {
      __syncthreads();  // protect Wp against readers of the previous stage
      // Stage W[t, p, qh*64 .. +64) -> Wp[t][q']
#pragma unroll
      for (int r = 0; r < 8; ++r) {
        const int flat = (r * 256 + tid) * 4;  // 0..8191 over [t][q']
        const int t = flat >> 6;
        const int q = flat & 63;
        const float4 v =
            *(const float4*)(W + (size_t)t * 16384 + (size_t)p * 128 + qh * 64 + q);
        Wp[t][q + 0] = v.x;
        Wp[t][q + 1] = v.y;
        Wp[t][q + 2] = v.z;
        Wp[t][q + 3] = v.w;
      }
      __syncthreads();

#pragma unroll 4
      for (int q = 0; q < 64; ++q) {
        const float4 h4 = *(const float4*)&hT[qh * 64 + q][m0];
        const float w0 = Wp[tt][q];
        const float w1 = Wp[tt + 32][q];
        const float w2 = Wp[tt + 64][q];
        const float w3 = Wp[tt + 96][q];
        inner[0][0] += w0 * h4.x; inner[0][1] += w0 * h4.y;
        inner[0][2] += w0 * h4.z; inner[0][3] += w0 * h4.w;
        inner[1][0] += w1 * h4.x; inner[1][1] += w1 * h4.y;
        inner[1][2] += w1 * h4.z; inner[1][3] += w1 * h4.w;
        inner[2][0] += w2 * h4.x; inner[2][1] += w2 * h4.y;
        inner[2][2] += w2 * h4.z; inner[2][3] += w2 * h4.w;
        inner[3][0] += w3 * h4.x; inner[3][1] += w3 * h4.y;
        inner[3][2] += w3 * h4.z; inner[3][3] += w3 * h4.w;
      }
    }

#pragma unroll
    for (int i = 0; i < 4; ++i)
#pragma unroll
      for (int j = 0; j < 4; ++j) acc[i][j] += tokv[j] * inner[i][j];
  }

  // Epilogue: act = tanh(acc + b_comp); delta = w_red[s]*(act - tanh(b_comp));
  // scatter-add into out[b, heads[b,s], :]
#pragma unroll
  for (int j = 0; j < 4; ++j) {
    const int m = blk * BM + m0 + j;
    const int b = m >> 11;
    const int s = m & 2047;
    const int head = heads[m];
    const float wr = w_red[s];
    float* orow = out + ((size_t)b * S_LEN + head) * T_DIM;
#pragma unroll
    for (int i = 0; i < 4; ++i) {
      const int t = tt + 32 * i;
      const float bc = b_comp[t];
      const float act = tanhf(acc[i][j] + bc);
      const float delta = wr * (act - tanhf(bc));
      atomicAdd(orow + t, delta);
    }
  }
}

// ---------------------------------------------------------------------------
extern "C" void kernel_launch(void* const* d_in, const int* in_sizes, int n_in,
                              void* d_out, int out_size, void* d_ws, size_t ws_size,
                              hipStream_t stream) {
  const float* tok    = (const float*)d_in[0];
  // d_in[1] = dep_embeddings: dead input (source bug), unused
  const int*   heads  = (const int*)d_in[2];
  const float* W      = (const float*)d_in[3];
  const float* b_comp = (const float*)d_in[4];
  const float* w_red  = (const float*)d_in[5];
  const float* b_red  = (const float*)d_in[6];
  float* out = (float*)d_out;

  init_out_kernel<<<2048, 256, 0, stream>>>(w_red, b_comp, b_red, out);
  main_kernel<<<M_TOTAL / BM, 256, 0, stream>>>(tok, heads, W, b_comp, w_red, out);
}

// Round 2
// 208.120 us; speedup vs baseline: 5.5504x; 5.5504x over previous
//
#include <hip/hip_runtime.h>
#include <hip/hip_fp16.h>
#include <math.h>

// Problem constants (B=8, S=2048, T=128)
#define S_LEN 2048
#define T_DIM 128
#define BM 64            // tokens per block
#define NBLK 256         // 16384 / BM
#define M_TOTAL 16384

typedef _Float16 half8 __attribute__((ext_vector_type(8)));
typedef float floatx16 __attribute__((ext_vector_type(16)));

// ---------------------------------------------------------------------------
// Kernel 0: W fp32 [t][p][q] -> W16 fp16 [p][t][q'] in d_ws, with XOR granule
// swizzle q' : granule g' = g ^ (t&15)  (granule = 8 f16 = 16 B; 16/row).
// The swizzle makes the main kernel's ds_read_b128 B-frag reads conflict-free
// while keeping the LDS image an exact contiguous copy of the global slab
// (required by global_load_lds wave-uniform-base semantics).
// ---------------------------------------------------------------------------
__global__ __launch_bounds__(256) void convert_w_kernel(
    const float* __restrict__ W, _Float16* __restrict__ W16) {
  const int p = blockIdx.x;
  const int tid = threadIdx.x;
#pragma unroll 4
  for (int i = 0; i < 64; ++i) {
    const int flat = i * 256 + tid;          // 0..16383 over [t][q']
    const int t = flat >> 7;
    const int qp = flat & 127;
    const int gp = qp >> 3;
    const int r = qp & 7;
    const int q = ((gp ^ (t & 15)) << 3) | r;
    W16[(size_t)p * 16384 + flat] =
        (_Float16)W[(size_t)t * 16384 + (size_t)p * 128 + q];
  }
}

// ---------------------------------------------------------------------------
// Kernel 1: out[b,i,t] = sum(w_red)*tanh(b_comp[t]) + b_red  (baseline row)
// ---------------------------------------------------------------------------
__global__ __launch_bounds__(256) void init_out_kernel(
    const float* __restrict__ w_red, const float* __restrict__ b_comp,
    const float* __restrict__ b_red, float* __restrict__ out) {
  __shared__ float red[4];
  const int tid = threadIdx.x;
  float part = 0.f;
#pragma unroll
  for (int i = 0; i < 8; ++i) part += w_red[tid * 8 + i];
#pragma unroll
  for (int off = 32; off > 0; off >>= 1) part += __shfl_down(part, off, 64);
  if ((tid & 63) == 0) red[tid >> 6] = part;
  __syncthreads();
  const float Sw = red[0] + red[1] + red[2] + red[3];
  const float br = b_red[0];
  const size_t base = (size_t)blockIdx.x * 1024 + (size_t)tid * 4;
  const int t0 = (int)(base & 127);
  float4 v;
  v.x = Sw * tanhf(b_comp[t0 + 0]) + br;
  v.y = Sw * tanhf(b_comp[t0 + 1]) + br;
  v.z = Sw * tanhf(b_comp[t0 + 2]) + br;
  v.w = Sw * tanhf(b_comp[t0 + 3]) + br;
  *(float4*)(out + base) = v;
}

// ---------------------------------------------------------------------------
// Kernel 2: MFMA main kernel.
// Per block: 64 tokens, 512 threads (8 waves, 2/SIMD, 1 block/CU via 96KB LDS).
// Wave (mh, th, kh): m-tile (32 rows) x t-half (2x32 cols) x k-half (64 of 128 q).
// Per p: A[m,q] = tok[m,p]*h[m,q] built in-register from p-invariant h16 VGPRs;
// B = W16 p-slice staged to LDS by global_load_lds (double-buffered).
// v_mfma_f32_32x32x16_f16: A lane: m=l&31, k=(l>>5)*8+j; B lane: n=l&31, same k;
// C/D: col=l&31, row=(r&3)+8*(r>>2)+4*(l>>5)   [guide §3, m74/m101-verified]
// ---------------------------------------------------------------------------
__global__ __launch_bounds__(512, 2) void main_kernel(
    const float* __restrict__ tok, const int* __restrict__ heads,
    const _Float16* __restrict__ W16, const float* __restrict__ b_comp,
    const float* __restrict__ w_red, float* __restrict__ out) {
  __shared__ _Float16 Wlds[2][16384];  // 64 KB double-buffered W p-slice
  __shared__ float tokT[128][64];      // 32 KB: tok transposed [p][m]

  const int tid = threadIdx.x;
  const int lane = tid & 63;
  const int wave = tid >> 6;  // 0..7
  const int mh = wave & 1;
  const int th = (wave >> 1) & 1;
  const int kh = wave >> 2;
  const int l31 = lane & 31;
  const int lh = lane >> 5;  // 0/1
  const int blk = blockIdx.x;
  const size_t tokbase = (size_t)blk * BM * T_DIM;

  // ---- setup: stage tokT (coalesced read, transposed scalar write) ----
#pragma unroll
  for (int i = 0; i < 4; ++i) {
    const int f4 = i * 512 + tid;  // 0..2047 float4s over [m][p]
    const int m = f4 >> 5;
    const int p0 = (f4 & 31) << 2;
    const float4 v = *(const float4*)(tok + tokbase + (size_t)m * 128 + p0);
    tokT[p0 + 0][m] = v.x;
    tokT[p0 + 1][m] = v.y;
    tokT[p0 + 2][m] = v.z;
    tokT[p0 + 3][m] = v.w;
  }

  // ---- setup: per-lane h16 fragments (p-invariant A building block) ----
  const int m_lane = mh * 32 + l31;
  half8 h16[4];
#pragma unroll
  for (int ks = 0; ks < 4; ++ks) {
    const int q0 = kh * 64 + ks * 16 + lh * 8;
    const float4 v0 = *(const float4*)(tok + tokbase + (size_t)m_lane * 128 + q0);
    const float4 v1 = *(const float4*)(tok + tokbase + (size_t)m_lane * 128 + q0 + 4);
    h16[ks][0] = (_Float16)tanhf(v0.x);
    h16[ks][1] = (_Float16)tanhf(v0.y);
    h16[ks][2] = (_Float16)tanhf(v0.z);
    h16[ks][3] = (_Float16)tanhf(v0.w);
    h16[ks][4] = (_Float16)tanhf(v1.x);
    h16[ks][5] = (_Float16)tanhf(v1.y);
    h16[ks][6] = (_Float16)tanhf(v1.z);
    h16[ks][7] = (_Float16)tanhf(v1.w);
  }

  // ---- staging helper: wave stages its 4KB chunk of the 32KB p-slice ----
  auto stage = [&](int buf, int p) {
    const _Float16* src = W16 + (size_t)p * 16384;
#pragma unroll
    for (int i = 0; i < 4; ++i) {
      const int off = (wave * 4 + i) * 512;  // f16 elems; wave-uniform base
      __builtin_amdgcn_global_load_lds(
          (const __attribute__((address_space(1))) void*)(src + off + lane * 8),
          (__attribute__((address_space(3))) void*)(&Wlds[buf][off]), 16, 0, 0);
    }
  };

  floatx16 acc[2];
#pragma unroll
  for (int tt = 0; tt < 2; ++tt)
#pragma unroll
    for (int r = 0; r < 16; ++r) acc[tt][r] = 0.f;

  stage(0, 0);
  __syncthreads();  // vmcnt(0) drain + barrier: buf0 ready

  int buf = 0;
  for (int p = 0; p < 128; ++p) {
    if (p + 1 < 128) stage(buf ^ 1, p + 1);

    // B fragments: 2 t-tiles x 4 ksteps, ds_read_b128 each (swizzled banks)
    half8 bfrag[2][4];
#pragma unroll
    for (int tt = 0; tt < 2; ++tt) {
      const int t = (th * 2 + tt) * 32 + l31;
#pragma unroll
      for (int ks = 0; ks < 4; ++ks) {
        const int g = kh * 8 + ks * 2 + lh;     // granule of 8 f16
        const int gp = g ^ (t & 15);            // undo conversion swizzle
        bfrag[tt][ks] = *(const half8*)(&Wlds[buf][t * 128 + gp * 8]);
      }
    }

    const _Float16 tokh = (_Float16)tokT[p][m_lane];
#pragma unroll
    for (int ks = 0; ks < 4; ++ks) {
      half8 a;
#pragma unroll
      for (int j = 0; j < 8; ++j) a[j] = tokh * h16[ks][j];
      acc[0] = __builtin_amdgcn_mfma_f32_32x32x16_f16(a, bfrag[0][ks], acc[0], 0, 0, 0);
      acc[1] = __builtin_amdgcn_mfma_f32_32x32x16_f16(a, bfrag[1][ks], acc[1], 0, 0, 0);
    }

    __syncthreads();  // readers of buf done; stage(buf^1) drained
    buf ^= 1;
  }

  // ---- k-half reduction via LDS (reuse Wlds as scratch) ----
  float* red = (float*)&Wlds[0][0];  // 32 KB used
  const int slot = wave & 3;         // (th,mh) identity, shared across kh pair
  if (kh == 1) {
#pragma unroll
    for (int tt = 0; tt < 2; ++tt)
#pragma unroll
      for (int r = 0; r < 16; ++r)
        red[((slot * 2 + tt) * 16 + r) * 64 + lane] = acc[tt][r];
  }
  __syncthreads();

  if (kh == 0) {
#pragma unroll
    for (int tt = 0; tt < 2; ++tt) {
#pragma unroll
      for (int r = 0; r < 16; ++r)
        acc[tt][r] += red[((slot * 2 + tt) * 16 + r) * 64 + lane];

      const int t = (th * 2 + tt) * 32 + l31;
      const float bc = b_comp[t];
      const float tbc = tanhf(bc);
#pragma unroll
      for (int r = 0; r < 16; ++r) {
        const int m_loc = (r & 3) + 8 * (r >> 2) + 4 * lh;
        const int m = blk * BM + mh * 32 + m_loc;
        const int b = m >> 11;
        const int s = m & 2047;
        const int head = heads[m];
        const float wr = w_red[s];
        const float act = tanhf(acc[tt][r] + bc);
        atomicAdd(out + ((size_t)b * S_LEN + head) * T_DIM + t, wr * (act - tbc));
      }
    }
  }
}

// ---------------------------------------------------------------------------
extern "C" void kernel_launch(void* const* d_in, const int* in_sizes, int n_in,
                              void* d_out, int out_size, void* d_ws, size_t ws_size,
                              hipStream_t stream) {
  const float* tok    = (const float*)d_in[0];
  // d_in[1] = dep_embeddings: dead input (source bug), unused
  const int*   heads  = (const int*)d_in[2];
  const float* W      = (const float*)d_in[3];
  const float* b_comp = (const float*)d_in[4];
  const float* w_red  = (const float*)d_in[5];
  const float* b_red  = (const float*)d_in[6];
  float* out = (float*)d_out;
  _Float16* W16 = (_Float16*)d_ws;  // 128*128*128 f16 = 4 MB

  convert_w_kernel<<<128, 256, 0, stream>>>(W, W16);
  init_out_kernel<<<2048, 256, 0, stream>>>(w_red, b_comp, b_red, out);
  main_kernel<<<NBLK, 512, 0, stream>>>(tok, heads, W16, b_comp, w_red, out);
}

// Round 3
// 169.225 us; speedup vs baseline: 6.8261x; 1.2298x over previous
//
#include <hip/hip_runtime.h>
#include <hip/hip_fp16.h>
#include <math.h>

// Problem constants (B=8, S=2048, T=128)
#define S_LEN 2048
#define T_DIM 128
#define BM 64            // tokens per block
#define NBLK 256         // 16384 / BM

typedef _Float16 half8 __attribute__((ext_vector_type(8)));
typedef float floatx16 __attribute__((ext_vector_type(16)));

// ---------------------------------------------------------------------------
// Kernel 0: W fp32 [t][p][q]  ->  W16f fp16 in MFMA-B-fragment order:
//   W16f[ ((p*4 + tc)*8 + kc)*512 + lane*8 + j ] = W[t, p, q]
//     t = tc*32 + (lane&31),  q = kc*16 + (lane>>5)*8 + j
// so a wave's B-fragment load in the main kernel is one coalesced 1KB
// global_load_dwordx4 (lane-contiguous). Block = (p, tc): grid 128x4.
// ---------------------------------------------------------------------------
__global__ __launch_bounds__(256) void convert_w_kernel(
    const float* __restrict__ W, _Float16* __restrict__ W16f) {
  const int p = blockIdx.x;
  const int tc = blockIdx.y;
  const int tid = threadIdx.x;
#pragma unroll
  for (int i = 0; i < 2; ++i) {
    const int idx8 = i * 256 + tid;    // 0..511: (kc, lane)
    const int kc = idx8 >> 6;
    const int l = idx8 & 63;
    const int t = tc * 32 + (l & 31);
    const int q = kc * 16 + (l >> 5) * 8;
    const float* src = W + (size_t)t * 16384 + (size_t)p * 128 + q;
    const float4 v0 = *(const float4*)(src);
    const float4 v1 = *(const float4*)(src + 4);
    half8 h;
    h[0] = (_Float16)v0.x; h[1] = (_Float16)v0.y;
    h[2] = (_Float16)v0.z; h[3] = (_Float16)v0.w;
    h[4] = (_Float16)v1.x; h[5] = (_Float16)v1.y;
    h[6] = (_Float16)v1.z; h[7] = (_Float16)v1.w;
    *(half8*)(W16f + (((size_t)p * 4 + tc) * 8 + kc) * 512 + l * 8) = h;
  }
}

// ---------------------------------------------------------------------------
// Kernel 1: out[b,i,t] = sum(w_red)*tanh(b_comp[t]) + b_red  (baseline row)
// ---------------------------------------------------------------------------
__global__ __launch_bounds__(256) void init_out_kernel(
    const float* __restrict__ w_red, const float* __restrict__ b_comp,
    const float* __restrict__ b_red, float* __restrict__ out) {
  __shared__ float red[4];
  const int tid = threadIdx.x;
  float part = 0.f;
#pragma unroll
  for (int i = 0; i < 8; ++i) part += w_red[tid * 8 + i];
#pragma unroll
  for (int off = 32; off > 0; off >>= 1) part += __shfl_down(part, off, 64);
  if ((tid & 63) == 0) red[tid >> 6] = part;
  __syncthreads();
  const float Sw = red[0] + red[1] + red[2] + red[3];
  const float br = b_red[0];
  const size_t base = (size_t)blockIdx.x * 1024 + (size_t)tid * 4;
  const int t0 = (int)(base & 127);
  float4 v;
  v.x = Sw * tanhf(b_comp[t0 + 0]) + br;
  v.y = Sw * tanhf(b_comp[t0 + 1]) + br;
  v.z = Sw * tanhf(b_comp[t0 + 2]) + br;
  v.w = Sw * tanhf(b_comp[t0 + 3]) + br;
  *(float4*)(out + base) = v;
}

// ---------------------------------------------------------------------------
// Kernel 2: barrier-free MFMA main kernel.
// 256 blocks x 512 threads (8 waves, 2/SIMD). Wave = (th: t-half of 64 cols,
// kh: k-chunk of 32 q). Each wave computes BOTH 32-row m-tiles -> B fragments
// have zero redundancy across the block; loaded straight from L2 (coalesced,
// fragment-ordered W16f), software-pipelined depth 1. NO __syncthreads in the
// p-loop. A[m,q] = tok[m,p]*h[m,q] built in-register (h p-invariant).
// v_mfma_f32_32x32x16_f16: A lane: m=l&31, k=(l>>5)*8+j; B: n=l&31, same k;
// C/D: col=l&31, row=(r&3)+8*(r>>2)+4*(l>>5)  [m74/m101-verified]
// ---------------------------------------------------------------------------
__global__ __launch_bounds__(512, 2) void main_kernel(
    const float* __restrict__ tok, const int* __restrict__ heads,
    const _Float16* __restrict__ W16f, const float* __restrict__ b_comp,
    const float* __restrict__ w_red, float* __restrict__ out) {
  __shared__ _Float16 tokT[128][64];  // 16 KB: tok transposed [p][m], f16
  __shared__ float red[2][64][128];   // 64 KB: k-partial reduction scratch

  const int tid = threadIdx.x;
  const int lane = tid & 63;
  const int wave = tid >> 6;  // 0..7
  const int th = wave & 1;    // t-half (64 cols)
  const int kh = wave >> 1;   // k-chunk (32 of 128 q)
  const int l31 = lane & 31;
  const int lh = lane >> 5;
  const int blk = blockIdx.x;
  const size_t tokbase = (size_t)blk * BM * T_DIM;

  // ---- stage tokT as f16 (coalesced read, transposed scalar write) ----
#pragma unroll
  for (int i = 0; i < 4; ++i) {
    const int f4 = i * 512 + tid;  // 0..2047 float4s over [m][p]
    const int m = f4 >> 5;
    const int p0 = (f4 & 31) << 2;
    const float4 v = *(const float4*)(tok + tokbase + (size_t)m * 128 + p0);
    tokT[p0 + 0][m] = (_Float16)v.x;
    tokT[p0 + 1][m] = (_Float16)v.y;
    tokT[p0 + 2][m] = (_Float16)v.z;
    tokT[p0 + 3][m] = (_Float16)v.w;
  }

  // ---- per-lane h fragments for this wave's k-chunk, both m-tiles ----
  half8 h16[2][2];  // [mh][ks]
#pragma unroll
  for (int mh = 0; mh < 2; ++mh) {
    const int m = mh * 32 + l31;
#pragma unroll
    for (int ks = 0; ks < 2; ++ks) {
      const int q0 = kh * 32 + ks * 16 + lh * 8;
      const float4 v0 = *(const float4*)(tok + tokbase + (size_t)m * 128 + q0);
      const float4 v1 = *(const float4*)(tok + tokbase + (size_t)m * 128 + q0 + 4);
      h16[mh][ks][0] = (_Float16)tanhf(v0.x);
      h16[mh][ks][1] = (_Float16)tanhf(v0.y);
      h16[mh][ks][2] = (_Float16)tanhf(v0.z);
      h16[mh][ks][3] = (_Float16)tanhf(v0.w);
      h16[mh][ks][4] = (_Float16)tanhf(v1.x);
      h16[mh][ks][5] = (_Float16)tanhf(v1.y);
      h16[mh][ks][6] = (_Float16)tanhf(v1.z);
      h16[mh][ks][7] = (_Float16)tanhf(v1.w);
    }
  }
  __syncthreads();  // tokT ready; last barrier before the p-loop

  // Per-wave fragment offsets within a p-slice (f16 elements):
  // off[tt][ks] = ((th*2+tt)*8 + kh*2+ks)*512 + lane*8
  int off[2][2];
#pragma unroll
  for (int tt = 0; tt < 2; ++tt)
#pragma unroll
    for (int ks = 0; ks < 2; ++ks)
      off[tt][ks] = (((th * 2 + tt) * 8 + kh * 2 + ks) << 9) + lane * 8;

  floatx16 acc[2][2];  // [mh][tt]
#pragma unroll
  for (int mh = 0; mh < 2; ++mh)
#pragma unroll
    for (int tt = 0; tt < 2; ++tt)
#pragma unroll
      for (int r = 0; r < 16; ++r) acc[mh][tt][r] = 0.f;

  half8 bf0[2][2], bf1[2][2];

  auto loadB = [&](half8 (&bf)[2][2], int p) {
    const _Float16* wp = W16f + (size_t)p * 16384;
#pragma unroll
    for (int tt = 0; tt < 2; ++tt)
#pragma unroll
      for (int ks = 0; ks < 2; ++ks)
        bf[tt][ks] = *(const half8*)(wp + off[tt][ks]);
  };

  auto compute = [&](half8 (&bf)[2][2], int p) {
    const _Float16 tokh0 = tokT[p][l31];
    const _Float16 tokh1 = tokT[p][32 + l31];
    half8 a0k0 = h16[0][0] * tokh0;
    half8 a0k1 = h16[0][1] * tokh0;
    half8 a1k0 = h16[1][0] * tokh1;
    half8 a1k1 = h16[1][1] * tokh1;
    acc[0][0] = __builtin_amdgcn_mfma_f32_32x32x16_f16(a0k0, bf[0][0], acc[0][0], 0, 0, 0);
    acc[0][1] = __builtin_amdgcn_mfma_f32_32x32x16_f16(a0k0, bf[1][0], acc[0][1], 0, 0, 0);
    acc[1][0] = __builtin_amdgcn_mfma_f32_32x32x16_f16(a1k0, bf[0][0], acc[1][0], 0, 0, 0);
    acc[1][1] = __builtin_amdgcn_mfma_f32_32x32x16_f16(a1k0, bf[1][0], acc[1][1], 0, 0, 0);
    acc[0][0] = __builtin_amdgcn_mfma_f32_32x32x16_f16(a0k1, bf[0][1], acc[0][0], 0, 0, 0);
    acc[0][1] = __builtin_amdgcn_mfma_f32_32x32x16_f16(a0k1, bf[1][1], acc[0][1], 0, 0, 0);
    acc[1][0] = __builtin_amdgcn_mfma_f32_32x32x16_f16(a1k1, bf[0][1], acc[1][0], 0, 0, 0);
    acc[1][1] = __builtin_amdgcn_mfma_f32_32x32x16_f16(a1k1, bf[1][1], acc[1][1], 0, 0, 0);
  };

  // Software pipeline, unroll-2, no barriers:
  loadB(bf0, 0);
  for (int p = 0; p < 128; p += 2) {
    loadB(bf1, p + 1);
    compute(bf0, p);
    if (p + 2 < 128) loadB(bf0, p + 2);
    compute(bf1, p + 1);
  }

  // ---- k-chunk reduction: 2 phases (kh even write, kh odd add) ----
  __syncthreads();
  float* R = &red[kh >> 1][0][0];  // kh{0,1}->red[0], kh{2,3}->red[1]
  if ((kh & 1) == 0) {
#pragma unroll
    for (int mh = 0; mh < 2; ++mh)
#pragma unroll
      for (int tt = 0; tt < 2; ++tt) {
        const int t = (th * 2 + tt) * 32 + l31;
#pragma unroll
        for (int r = 0; r < 16; ++r) {
          const int m = mh * 32 + (r & 3) + 8 * (r >> 2) + 4 * lh;
          R[m * 128 + t] = acc[mh][tt][r];
        }
      }
  }
  __syncthreads();
  if ((kh & 1) == 1) {
#pragma unroll
    for (int mh = 0; mh < 2; ++mh)
#pragma unroll
      for (int tt = 0; tt < 2; ++tt) {
        const int t = (th * 2 + tt) * 32 + l31;
#pragma unroll
        for (int r = 0; r < 16; ++r) {
          const int m = mh * 32 + (r & 3) + 8 * (r >> 2) + 4 * lh;
          R[m * 128 + t] += acc[mh][tt][r];
        }
      }
  }
  __syncthreads();

  // ---- epilogue: all 512 threads; t fixed per thread, 16 m's each ----
  const int t = tid & 127;
  const float bc = b_comp[t];
  const float tbc = tanhf(bc);
#pragma unroll
  for (int it = 0; it < 16; ++it) {
    const int m = it * 4 + (tid >> 7);
    const float v = red[0][m][t] + red[1][m][t];
    const int gm = blk * BM + m;
    const int b = gm >> 11;
    const int s = gm & 2047;
    const int head = heads[gm];
    const float wr = w_red[s];
    atomicAdd(out + ((size_t)b * S_LEN + head) * T_DIM + t,
              wr * (tanhf(v + bc) - tbc));
  }
}

// ---------------------------------------------------------------------------
extern "C" void kernel_launch(void* const* d_in, const int* in_sizes, int n_in,
                              void* d_out, int out_size, void* d_ws, size_t ws_size,
                              hipStream_t stream) {
  const float* tok    = (const float*)d_in[0];
  // d_in[1] = dep_embeddings: dead input (source bug), unused
  const int*   heads  = (const int*)d_in[2];
  const float* W      = (const float*)d_in[3];
  const float* b_comp = (const float*)d_in[4];
  const float* w_red  = (const float*)d_in[5];
  const float* b_red  = (const float*)d_in[6];
  float* out = (float*)d_out;
  _Float16* W16f = (_Float16*)d_ws;  // 128*128*128 f16 = 4 MB, fragment-ordered

  convert_w_kernel<<<dim3(128, 4), 256, 0, stream>>>(W, W16f);
  init_out_kernel<<<2048, 256, 0, stream>>>(w_red, b_comp, b_red, out);
  main_kernel<<<NBLK, 512, 0, stream>>>(tok, heads, W16f, b_comp, w_red, out);
}